// Round 7
// baseline (3284.653 us; speedup 1.0000x reference)
//
#include <hip/hip_runtime.h>
#include <math.h>

#define BATCH 8
#define NPTS 2048
#define KNN 20
#define BN_TOTAL (BATCH * NPTS)
#define EPSV 1e-5f
#define NPH 4     // j-phases per row (each phase = 4 tiles of 128 cols)
#define NCAND (NPH * KNN)   // 80 candidates per row

typedef __attribute__((ext_vector_type(8))) short short8v;   // 8 bf16
typedef __attribute__((ext_vector_type(4))) float floatx4;

// ---------------------------------------------------------------------------
// x2: per-row sum of squares
// ---------------------------------------------------------------------------
__global__ __launch_bounds__(256) void x2_kernel(const float* __restrict__ x, int C, int ldx,
                                                 float* __restrict__ x2) {
    int i = blockIdx.x * 256 + threadIdx.x;
    if (i >= BN_TOTAL) return;
    const float* xr = x + (size_t)i * ldx;
    float s = 0.f;
    if ((ldx & 3) == 0 && (C & 3) == 0) {
        const float4* xr4 = (const float4*)xr;
        for (int c = 0; c < (C >> 2); ++c) {
            float4 v = xr4[c];
            s = fmaf(v.x, v.x, s); s = fmaf(v.y, v.y, s);
            s = fmaf(v.z, v.z, s); s = fmaf(v.w, v.w, s);
        }
    } else {
        for (int c = 0; c < C; ++c) s = fmaf(xr[c], xr[c], s);
    }
    x2[i] = s;
}

// ---------------------------------------------------------------------------
// knn_phase: block = 128 query rows x 512 cols (4 serial tiles of 128).
// GEMM identical to round-4/6 (same FMA order -> identical fp32 distances).
// Running per-row top-20 in registers (2 slots/lane across 16 lanes):
//   tile 0: exact 20-iteration extraction (warm-up)
//   tiles 1-3: ballot-gated insert-evict, threshold = running 20th (vmin)
// Ties: insert priority (val desc, j asc); evict among equal mins -> largest j
// => exact jax.lax.top_k tie set. cand[row][ph*20+slot] = (val, j).
// ---------------------------------------------------------------------------
template <int C, int LDX>
__global__ __launch_bounds__(256) void knn_phase(const float* __restrict__ x,
                                                 const float* __restrict__ x2,
                                                 float2* __restrict__ cand) {
    constexpr int KT = (C + 15) / 16;
    constexpr int KR = KT * 16;
    __shared__ float Af[KR][132];     // [k][row] for the block's 128 rows
    __shared__ float Bs[16][132];     // [k][col] per (jt, kt)

    int tid = threadIdx.x;
    int b = blockIdx.z;
    int ph = blockIdx.y;
    int i0 = blockIdx.x * 128;
    const float* xb = x + (size_t)b * NPTS * LDX;
    const float* x2b = x2 + (b << 11);
    int tm = tid >> 4, tn = tid & 15;
    int gsh = ((tid >> 4) & 3) << 4;          // 16-lane group shift within wave

    // stage Af once
    if (LDX == 3) {
        for (int e = tid; e < 128 * 4; e += 256) {
            int r = e >> 2, c4 = e & 3;
#pragma unroll
            for (int u = 0; u < 4; ++u) {
                int kk = c4 * 4 + u;
                Af[kk][r] = (kk < C) ? xb[(size_t)(i0 + r) * LDX + kk] : 0.f;
            }
        }
    } else {
        for (int e = tid; e < 128 * KT * 4; e += 256) {
            int r = e / (KT * 4), c4 = e % (KT * 4);
            float4 v = *(const float4*)&xb[(size_t)(i0 + r) * LDX + c4 * 4];
            Af[c4 * 4 + 0][r] = v.x; Af[c4 * 4 + 1][r] = v.y;
            Af[c4 * 4 + 2][r] = v.z; Af[c4 * 4 + 3][r] = v.w;
        }
    }

    // per-row selection state (mi-indexed, statically unrolled accesses only)
    float s0v[8], s1v[8], vmin[8];
    int s0j[8], s1j[8];
#pragma unroll
    for (int mi = 0; mi < 8; ++mi) {
        s0v[mi] = -INFINITY; s0j[mi] = 0x7fffffff;
        s1v[mi] = (tn < 4) ? -INFINITY : INFINITY;   // +INF dummies never evicted
        s1j[mi] = 0x7fffffff;
        vmin[mi] = -INFINITY;
    }
    float x2i[8];
#pragma unroll
    for (int mi = 0; mi < 8; ++mi) x2i[mi] = x2b[i0 + tm * 8 + mi];

    for (int jt = 0; jt < 4; ++jt) {
        int j0 = ph * 512 + jt * 128;
        float acc[8][8];
#pragma unroll
        for (int mi = 0; mi < 8; ++mi)
#pragma unroll
            for (int ni = 0; ni < 8; ++ni) acc[mi][ni] = 0.f;

        for (int kt = 0; kt < KT; ++kt) {
            int k0 = kt << 4;
            __syncthreads();
            if (LDX == 3) {
                for (int e = tid; e < 512; e += 256) {
                    int col = e >> 2, c4 = e & 3;
#pragma unroll
                    for (int u = 0; u < 4; ++u) {
                        int kk = c4 * 4 + u;
                        Bs[kk][col] = (kk < C) ? xb[(size_t)(j0 + col) * LDX + kk] : 0.f;
                    }
                }
            } else {
                for (int e = tid; e < 512; e += 256) {
                    int col = e >> 2, c4 = e & 3;
                    float4 v = *(const float4*)&xb[(size_t)(j0 + col) * LDX + k0 + c4 * 4];
                    Bs[c4 * 4 + 0][col] = v.x; Bs[c4 * 4 + 1][col] = v.y;
                    Bs[c4 * 4 + 2][col] = v.z; Bs[c4 * 4 + 3][col] = v.w;
                }
            }
            __syncthreads();
#pragma unroll
            for (int k = 0; k < 16; ++k) {
                float4 a0 = *(const float4*)&Af[k0 + k][tm * 8];
                float4 a1 = *(const float4*)&Af[k0 + k][tm * 8 + 4];
                float4 c0 = *(const float4*)&Bs[k][tn * 8];
                float4 c1 = *(const float4*)&Bs[k][tn * 8 + 4];
                float av[8] = {a0.x, a0.y, a0.z, a0.w, a1.x, a1.y, a1.z, a1.w};
                float bv[8] = {c0.x, c0.y, c0.z, c0.w, c1.x, c1.y, c1.z, c1.w};
#pragma unroll
                for (int mi = 0; mi < 8; ++mi)
#pragma unroll
                    for (int ni = 0; ni < 8; ++ni)
                        acc[mi][ni] = fmaf(av[mi], bv[ni], acc[mi][ni]);
            }
        }

        // finalize neg-dists (identical arithmetic to prior rounds)
        float x2j[8];
#pragma unroll
        for (int u = 0; u < 8; ++u) x2j[u] = x2b[j0 + tn * 8 + u];
#pragma unroll
        for (int mi = 0; mi < 8; ++mi)
#pragma unroll
            for (int ni = 0; ni < 8; ++ni)
                acc[mi][ni] = 2.f * acc[mi][ni] - x2i[mi] - x2j[ni];

        if (jt == 0) {
            // exact top-20 extraction (warm-up), winners -> slots
#pragma unroll
            for (int mi = 0; mi < 8; ++mi) {
                float lv = acc[mi][0]; int lu = 0;
#pragma unroll
                for (int u = 1; u < 8; ++u)
                    if (acc[mi][u] > lv) { lv = acc[mi][u]; lu = u; }
                int lj = j0 + tn * 8 + lu;
#pragma unroll 1
                for (int it = 0; it < KNN; ++it) {
                    float bv = lv; int bj = lj;
#pragma unroll
                    for (int d = 1; d < 16; d <<= 1) {
                        float ov = __shfl_xor(bv, d);
                        int oj = __shfl_xor(bj, d);
                        if (ov > bv || (ov == bv && oj < bj)) { bv = ov; bj = oj; }
                    }
                    if (it < 16) { if (tn == it) { s0v[mi] = bv; s0j[mi] = bj; } }
                    else if (tn == it - 16) { s1v[mi] = bv; s1j[mi] = bj; }
                    if (bj == lj) {
#pragma unroll
                        for (int u = 0; u < 8; ++u)
                            acc[mi][u] = (j0 + tn * 8 + u == bj) ? -INFINITY : acc[mi][u];
                        lv = acc[mi][0]; lu = 0;
#pragma unroll
                        for (int u = 1; u < 8; ++u)
                            if (acc[mi][u] > lv) { lv = acc[mi][u]; lu = u; }
                        lj = j0 + tn * 8 + lu;
                    }
                }
                float mv = fminf(s0v[mi], s1v[mi]);
#pragma unroll
                for (int d = 1; d < 16; d <<= 1) mv = fminf(mv, __shfl_xor(mv, d));
                vmin[mi] = mv;
            }
        } else {
            // pruned incremental insert
#pragma unroll
            for (int mi = 0; mi < 8; ++mi) {
                float lv = acc[mi][0]; int lu = 0;
#pragma unroll
                for (int u = 1; u < 8; ++u)
                    if (acc[mi][u] > lv) { lv = acc[mi][u]; lu = u; }
                int lj = j0 + tn * 8 + lu;
                unsigned short grp = (unsigned short)(__ballot(lv > vmin[mi]) >> gsh);
                while (grp) {
                    // winner argmax (val desc, j asc)
                    float bv = lv; int bj = lj;
#pragma unroll
                    for (int d = 1; d < 16; d <<= 1) {
                        float ov = __shfl_xor(bv, d);
                        int oj = __shfl_xor(bj, d);
                        if (ov > bv || (ov == bv && oj < bj)) { bv = ov; bj = oj; }
                    }
                    // evictee argmin over 32 slots (val asc, j desc, slot asc)
                    bool p1 = (s1v[mi] < s0v[mi]) || (s1v[mi] == s0v[mi] && s1j[mi] > s0j[mi]);
                    float ev = p1 ? s1v[mi] : s0v[mi];
                    int ej = p1 ? s1j[mi] : s0j[mi];
                    int ei = (tn << 1) | (p1 ? 1 : 0);
#pragma unroll
                    for (int d = 1; d < 16; d <<= 1) {
                        float ov = __shfl_xor(ev, d);
                        int oj = __shfl_xor(ej, d);
                        int oi = __shfl_xor(ei, d);
                        if (ov < ev || (ov == ev && (oj > ej || (oj == ej && oi < ei)))) {
                            ev = ov; ej = oj; ei = oi;
                        }
                    }
                    bool own0 = (ei == (tn << 1));
                    bool own1 = (ei == ((tn << 1) | 1));
                    s0v[mi] = own0 ? bv : s0v[mi]; s0j[mi] = own0 ? bj : s0j[mi];
                    s1v[mi] = own1 ? bv : s1v[mi]; s1j[mi] = own1 ? bj : s1j[mi];
                    float mv = fminf(s0v[mi], s1v[mi]);
#pragma unroll
                    for (int d = 1; d < 16; d <<= 1) mv = fminf(mv, __shfl_xor(mv, d));
                    vmin[mi] = mv;
                    if (bj == lj) {   // winner owner consumes and rescans
#pragma unroll
                        for (int u = 0; u < 8; ++u)
                            acc[mi][u] = (j0 + tn * 8 + u == bj) ? -INFINITY : acc[mi][u];
                        lv = acc[mi][0]; lu = 0;
#pragma unroll
                        for (int u = 1; u < 8; ++u)
                            if (acc[mi][u] > lv) { lv = acc[mi][u]; lu = u; }
                        lj = j0 + tn * 8 + lu;
                    }
                    grp = (unsigned short)(__ballot(lv > vmin[mi]) >> gsh);
                }
            }
        }
    }

    // write the phase's 20 (val, j) per row
#pragma unroll
    for (int mi = 0; mi < 8; ++mi) {
        float2* cr = cand + ((size_t)(b << 11) + i0 + tm * 8 + mi) * NCAND + ph * KNN;
        cr[tn] = make_float2(s0v[mi], __int_as_float(s0j[mi]));
        if (tn < 4) cr[16 + tn] = make_float2(s1v[mi], __int_as_float(s1j[mi]));
    }
}

// ---------------------------------------------------------------------------
// ktop_merge: one wave per row; 80 candidates (unique j) -> final top-20.
// ---------------------------------------------------------------------------
__global__ __launch_bounds__(256) void ktop_merge(const float2* __restrict__ cand,
                                                  int* __restrict__ idx_out) {
    int lane = threadIdx.x & 63, w = threadIdx.x >> 6;
    int row = blockIdx.x * 4 + w;
    const float2* cr = cand + (size_t)row * NCAND;
    float v[2]; int j[2];
    { float2 c = cr[lane]; v[0] = c.x; j[0] = __float_as_int(c.y); }
    if (lane < NCAND - 64) {
        float2 c = cr[64 + lane]; v[1] = c.x; j[1] = __float_as_int(c.y);
    } else { v[1] = -INFINITY; j[1] = 0x7fffffff; }

    float lv; int lj;
    bool p1 = (v[1] > v[0]) || (v[1] == v[0] && j[1] < j[0]);
    lv = p1 ? v[1] : v[0]; lj = p1 ? j[1] : j[0];

    int sel = 0;
#pragma unroll 1
    for (int it = 0; it < KNN; ++it) {
        float bv = lv; int bj = lj;
#pragma unroll
        for (int d = 1; d < 64; d <<= 1) {
            float ov = __shfl_xor(bv, d);
            int oj = __shfl_xor(bj, d);
            if (ov > bv || (ov == bv && oj < bj)) { bv = ov; bj = oj; }
        }
        if (lane == it) sel = bj;
        if (j[0] == bj) { v[0] = -INFINITY; j[0] = 0x7fffffff; }
        if (j[1] == bj) { v[1] = -INFINITY; j[1] = 0x7fffffff; }
        bool q1 = (v[1] > v[0]) || (v[1] == v[0] && j[1] < j[0]);
        lv = q1 ? v[1] : v[0]; lj = q1 ? j[1] : j[0];
    }
    if (lane < KNN) idx_out[(size_t)row * KNN + lane] = sel;
}

// ---------------------------------------------------------------------------
// pq_gemm: PQ[bn][0..O)=x.Wp^T, PQ[bn][O..2O)=x.Wq^T as one GEMM (N=2O).
// ---------------------------------------------------------------------------
__global__ __launch_bounds__(256) void pq_gemm(const float* __restrict__ X, int C, int ldx,
                                               const float* __restrict__ W, int O,
                                               float* __restrict__ PQ) {
    __shared__ float As[32][68];
    __shared__ float Bs[32][68];
    int i0 = blockIdx.x * 64, j0 = blockIdx.y * 64;
    int tid = threadIdx.x;
    int tm = tid >> 4, tn = tid & 15;
    int N2 = 2 * O;

    float acc[4][4] = {};
    int KT = (C + 31) >> 5;
    for (int kt = 0; kt < KT; ++kt) {
        int k0 = kt << 5;
        for (int e = tid; e < 2048; e += 256) {
            int m = e >> 5, k = e & 31;
            int kk = k0 + k;
            As[k][m] = (kk < C) ? X[(size_t)(i0 + m) * ldx + kk] : 0.f;
            int o = j0 + m;
            float wv = 0.f;
            if (kk < C)
                wv = (o < O) ? W[(size_t)o * 2 * C + kk] : W[(size_t)(o - O) * 2 * C + C + kk];
            Bs[k][m] = wv;
        }
        __syncthreads();
#pragma unroll
        for (int k = 0; k < 32; ++k) {
            float4 a = *(const float4*)&As[k][tm * 4];
            float4 bb = *(const float4*)&Bs[k][tn * 4];
            float av[4] = {a.x, a.y, a.z, a.w};
            float bv[4] = {bb.x, bb.y, bb.z, bb.w};
#pragma unroll
            for (int mi = 0; mi < 4; ++mi)
#pragma unroll
                for (int ni = 0; ni < 4; ++ni)
                    acc[mi][ni] = fmaf(av[mi], bv[ni], acc[mi][ni]);
        }
        __syncthreads();
    }
#pragma unroll
    for (int mi = 0; mi < 4; ++mi) {
        float4 o;
        o.x = acc[mi][0]; o.y = acc[mi][1]; o.z = acc[mi][2]; o.w = acc[mi][3];
        *(float4*)&PQ[(size_t)(i0 + tm * 4 + mi) * N2 + j0 + tn * 4] = o;
    }
}

// ---------------------------------------------------------------------------
// gather-max + BN + LeakyReLU epilogue. 256/O rows per block, all lanes busy.
// ---------------------------------------------------------------------------
__global__ __launch_bounds__(256) void gmax_kernel(const float* __restrict__ PQ,
                                                   const int* __restrict__ idx, int O, int oshift,
                                                   const float* __restrict__ gamma,
                                                   const float* __restrict__ beta,
                                                   float* __restrict__ out, int ldo) {
    __shared__ int s_idx[4][KNN];
    int rpb = 256 >> oshift;                 // O in {64,128,256}
    int lr = threadIdx.x >> oshift;
    int o = threadIdx.x & (O - 1);
    int bn = blockIdx.x * rpb + lr;
    int b = bn >> 11;
    if (o < KNN) s_idx[lr][o] = idx[bn * KNN + o];
    __syncthreads();
    const float inv = 1.0f / sqrtf(1.0f + EPSV);
    int N2 = 2 * O;
    size_t brow = (size_t)(b << 11);
    float mx = -INFINITY, mn = INFINITY;
#pragma unroll
    for (int k = 0; k < KNN; ++k) {
        float v = PQ[(brow + s_idx[lr][k]) * N2 + o];
        mx = fmaxf(mx, v);
        mn = fminf(mn, v);
    }
    float pn = PQ[(size_t)bn * N2 + o];
    float qn = PQ[(size_t)bn * N2 + O + o];
    float sc = gamma[o] * inv;
    float m = (sc >= 0.f) ? mx : mn;
    float z = sc * (m - pn + qn) + beta[o];
    out[(size_t)bn * ldo + o] = (z >= 0.f) ? z : 0.2f * z;
}

// ---------------------------------------------------------------------------
// split_bf16: x -> (hi, lo) bf16 pair, RNE.
// ---------------------------------------------------------------------------
__device__ __forceinline__ unsigned short bf16_rne(float x) {
    union { float f; unsigned u; } cv; cv.f = x;
    unsigned r = (cv.u + 0x7fffu + ((cv.u >> 16) & 1u)) >> 16;
    return (unsigned short)r;
}
__global__ __launch_bounds__(256) void split_bf16_kernel(const float* __restrict__ in, int n4,
                                                         unsigned short* __restrict__ hi,
                                                         unsigned short* __restrict__ lo) {
    int i = blockIdx.x * 256 + threadIdx.x;
    if (i >= n4) return;
    float4 v = ((const float4*)in)[i];
    float vv[4] = {v.x, v.y, v.z, v.w};
    ushort4 h, l;
    unsigned short hh[4], ll[4];
#pragma unroll
    for (int u = 0; u < 4; ++u) {
        unsigned short hb = bf16_rne(vv[u]);
        union { unsigned u32; float f; } hf; hf.u32 = ((unsigned)hb) << 16;
        hh[u] = hb;
        ll[u] = bf16_rne(vv[u] - hf.f);
    }
    h.x = hh[0]; h.y = hh[1]; h.z = hh[2]; h.w = hh[3];
    l.x = ll[0]; l.y = ll[1]; l.z = ll[2]; l.w = ll[3];
    *(ushort4*)(hi + (size_t)i * 4) = h;
    *(ushort4*)(lo + (size_t)i * 4) = l;
}

// ---------------------------------------------------------------------------
// final MFMA GEMM: feat = lrelu(bn(X @ W5^T)) with split-bf16 (3 K-segments),
// fused partial max/sum over the 128 n-rows. 128x128 tile, BK=32, 4 waves.
// ---------------------------------------------------------------------------
__global__ __launch_bounds__(256) void final_mfma(const unsigned short* __restrict__ Xhi,
                                                  const unsigned short* __restrict__ Xlo,
                                                  const unsigned short* __restrict__ Whi,
                                                  const unsigned short* __restrict__ Wlo,
                                                  const float* __restrict__ g5,
                                                  const float* __restrict__ b5,
                                                  float* __restrict__ part) {
    __shared__ __align__(16) char As[128 * 64];
    __shared__ __align__(16) char Bs[128 * 64];
    __shared__ float sredM[2][128];
    __shared__ float sredS[2][128];

    int tid = threadIdx.x;
    int i0 = blockIdx.x * 128;
    int j0 = blockIdx.y * 128;
    int lane = tid & 63, w = tid >> 6;
    int wr = w >> 1, wc = w & 1;

    int rowA = tid >> 2, q = tid & 3;
    auto swz = [](int row, int qq) { return (row * 64 + qq * 16) ^ ((row & 7) << 4); };
    int wa0 = swz(rowA, q), wa1 = swz(rowA + 64, q);

    int fr = lane & 15, slot = lane >> 4;
    int aoff[4], boff[4];
#pragma unroll
    for (int m = 0; m < 4; ++m) {
        int ra = wr * 64 + m * 16 + fr;
        aoff[m] = (ra * 64 + slot * 16) ^ ((ra & 7) << 4);
        int rb = wc * 64 + m * 16 + fr;
        boff[m] = (rb * 64 + slot * 16) ^ ((rb & 7) << 4);
    }

    floatx4 acc[4][4];
#pragma unroll
    for (int m = 0; m < 4; ++m)
#pragma unroll
        for (int n = 0; n < 4; ++n)
            acc[m][n] = (floatx4){0.f, 0.f, 0.f, 0.f};

    uint4 ra0, ra1, rb0, rb1;
    auto prefetch = [&](int it) {
        int seg = it >> 4;
        int kk = (it & 15) * 32;
        const unsigned short* Ab = ((seg < 2) ? Xhi : Xlo) + (size_t)i0 * 512 + kk + q * 8;
        const unsigned short* Bb = ((seg == 1) ? Wlo : Whi) + (size_t)j0 * 512 + kk + q * 8;
        ra0 = *(const uint4*)(Ab + (size_t)rowA * 512);
        ra1 = *(const uint4*)(Ab + (size_t)(rowA + 64) * 512);
        rb0 = *(const uint4*)(Bb + (size_t)rowA * 512);
        rb1 = *(const uint4*)(Bb + (size_t)(rowA + 64) * 512);
    };

    prefetch(0);
    for (int it = 0; it < 48; ++it) {
        __syncthreads();
        *(uint4*)(As + wa0) = ra0;
        *(uint4*)(As + wa1) = ra1;
        *(uint4*)(Bs + wa0) = rb0;
        *(uint4*)(Bs + wa1) = rb1;
        __syncthreads();
        if (it < 47) prefetch(it + 1);
        short8v af[4], bf[4];
#pragma unroll
        for (int m = 0; m < 4; ++m) af[m] = *(const short8v*)(As + aoff[m]);
#pragma unroll
        for (int n = 0; n < 4; ++n) bf[n] = *(const short8v*)(Bs + boff[n]);
#pragma unroll
        for (int m = 0; m < 4; ++m)
#pragma unroll
            for (int n = 0; n < 4; ++n)
                acc[m][n] = __builtin_amdgcn_mfma_f32_16x16x32_bf16(af[m], bf[n], acc[m][n], 0, 0, 0);
    }

    const float inv = 1.0f / sqrtf(1.0f + EPSV);
#pragma unroll
    for (int n = 0; n < 4; ++n) {
        int o = j0 + wc * 64 + n * 16 + fr;
        float sc = g5[o] * inv;
        float bi = b5[o];
        float mx = -INFINITY, sm = 0.f;
#pragma unroll
        for (int m = 0; m < 4; ++m)
#pragma unroll
            for (int r = 0; r < 4; ++r) {
                float z = fmaf(sc, acc[m][n][r], bi);
                z = (z >= 0.f) ? z : 0.2f * z;
                mx = fmaxf(mx, z);
                sm += z;
            }
#pragma unroll
        for (int d = 16; d < 64; d <<= 1) {
            mx = fmaxf(mx, __shfl_xor(mx, d));
            sm += __shfl_xor(sm, d);
        }
        if (slot == 0) {
            sredM[wr][wc * 64 + n * 16 + fr] = mx;
            sredS[wr][wc * 64 + n * 16 + fr] = sm;
        }
    }
    __syncthreads();
    if (tid < 128) {
        float m = fmaxf(sredM[0][tid], sredM[1][tid]);
        float s = sredS[0][tid] + sredS[1][tid];
        int b = i0 >> 11, nt = (i0 >> 7) & 15;
        size_t base = (size_t)((b * 16 + nt) * 2) * 1024 + j0 + tid;
        part[base] = m;
        part[base + 1024] = s;
    }
}

__global__ __launch_bounds__(256) void freduce_kernel(const float* __restrict__ part,
                                                      float* __restrict__ out) {
    int t = blockIdx.x * 256 + threadIdx.x;
    if (t >= 8 * 1024) return;
    int b = t >> 10, o = t & 1023;
    float m = -INFINITY, s = 0.f;
#pragma unroll
    for (int nt = 0; nt < 16; ++nt) {
        size_t base = (size_t)((b * 16 + nt) * 2) * 1024 + o;
        m = fmaxf(m, part[base]);
        s += part[base + 1024];
    }
    out[b * 2048 + o] = m;
    out[b * 2048 + 1024 + o] = s * (1.0f / 2048.0f);
}

// ---------------------------------------------------------------------------
extern "C" void kernel_launch(void* const* d_in, const int* in_sizes, int n_in,
                              void* d_out, int out_size, void* d_ws, size_t ws_size,
                              hipStream_t stream) {
    const float* points = (const float*)d_in[0];
    const float* W1 = (const float*)d_in[1];
    const float* W2 = (const float*)d_in[2];
    const float* W3 = (const float*)d_in[3];
    const float* W4 = (const float*)d_in[4];
    const float* W5 = (const float*)d_in[5];
    const float* g1 = (const float*)d_in[6];
    const float* b1 = (const float*)d_in[7];
    const float* g2 = (const float*)d_in[8];
    const float* b2 = (const float*)d_in[9];
    const float* g3 = (const float*)d_in[10];
    const float* b3 = (const float*)d_in[11];
    const float* g4 = (const float*)d_in[12];
    const float* b4 = (const float*)d_in[13];
    const float* g5 = (const float*)d_in[14];
    const float* b5 = (const float*)d_in[15];
    float* out = (float*)d_out;

    const size_t f_xcat = (size_t)BN_TOTAL * 512;            // 8.4M floats
    const size_t f_w5 = (size_t)1024 * 512;
    const size_t f_union = (size_t)BN_TOTAL * 320 * 2;       // covers SPQ/cand/bf16
    const size_t f_x2 = BN_TOTAL;
    const size_t f_idx = (size_t)BN_TOTAL * KNN;             // ints
    const size_t f_part = (size_t)8 * 16 * 2 * 1024;

    float* xcat = (float*)d_ws;
    float* U = xcat + f_xcat;               // union: SPQ | cand | bf16 buffers
    float* SPQ = U;
    float2* cand = (float2*)U;
    unsigned short* Xhi = (unsigned short*)U;
    unsigned short* Xlo = Xhi + f_xcat;
    unsigned short* Whi = Xlo + f_xcat;
    unsigned short* Wlo = Whi + f_w5;
    float* x2 = U + f_union;
    int* idx = (int*)(x2 + f_x2);
    float* part = (float*)(idx + f_idx);

    // ---- layer 1 (C=3 -> O=64)
    x2_kernel<<<64, 256, 0, stream>>>(points, 3, 3, x2);
    knn_phase<3, 3><<<dim3(16, NPH, 8), 256, 0, stream>>>(points, x2, cand);
    ktop_merge<<<BN_TOTAL / 4, 256, 0, stream>>>(cand, idx);
    pq_gemm<<<dim3(256, 2), 256, 0, stream>>>(points, 3, 3, W1, 64, SPQ);
    gmax_kernel<<<BN_TOTAL / 4, 256, 0, stream>>>(SPQ, idx, 64, 6, g1, b1, xcat + 0, 512);

    // ---- layer 2 (C=64 -> O=64)
    x2_kernel<<<64, 256, 0, stream>>>(xcat + 0, 64, 512, x2);
    knn_phase<64, 512><<<dim3(16, NPH, 8), 256, 0, stream>>>(xcat + 0, x2, cand);
    ktop_merge<<<BN_TOTAL / 4, 256, 0, stream>>>(cand, idx);
    pq_gemm<<<dim3(256, 2), 256, 0, stream>>>(xcat + 0, 64, 512, W2, 64, SPQ);
    gmax_kernel<<<BN_TOTAL / 4, 256, 0, stream>>>(SPQ, idx, 64, 6, g2, b2, xcat + 64, 512);

    // ---- layer 3 (C=64 -> O=128)
    x2_kernel<<<64, 256, 0, stream>>>(xcat + 64, 64, 512, x2);
    knn_phase<64, 512><<<dim3(16, NPH, 8), 256, 0, stream>>>(xcat + 64, x2, cand);
    ktop_merge<<<BN_TOTAL / 4, 256, 0, stream>>>(cand, idx);
    pq_gemm<<<dim3(256, 4), 256, 0, stream>>>(xcat + 64, 64, 512, W3, 128, SPQ);
    gmax_kernel<<<BN_TOTAL / 2, 256, 0, stream>>>(SPQ, idx, 128, 7, g3, b3, xcat + 128, 512);

    // ---- layer 4 (C=128 -> O=256)
    x2_kernel<<<64, 256, 0, stream>>>(xcat + 128, 128, 512, x2);
    knn_phase<128, 512><<<dim3(16, NPH, 8), 256, 0, stream>>>(xcat + 128, x2, cand);
    ktop_merge<<<BN_TOTAL / 4, 256, 0, stream>>>(cand, idx);
    pq_gemm<<<dim3(256, 8), 256, 0, stream>>>(xcat + 128, 128, 512, W4, 256, SPQ);
    gmax_kernel<<<BN_TOTAL, 256, 0, stream>>>(SPQ, idx, 256, 8, g4, b4, xcat + 256, 512);

    // ---- final layer
    split_bf16_kernel<<<(int)((f_xcat / 4 + 255) / 256), 256, 0, stream>>>(xcat, (int)(f_xcat / 4), Xhi, Xlo);
    split_bf16_kernel<<<(int)((f_w5 / 4 + 255) / 256), 256, 0, stream>>>(W5, (int)(f_w5 / 4), Whi, Wlo);
    final_mfma<<<dim3(BN_TOTAL / 128, 1024 / 128), 256, 0, stream>>>(Xhi, Xlo, Whi, Wlo, g5, b5, part);
    freduce_kernel<<<(8 * 1024 + 255) / 256, 256, 0, stream>>>(part, out);
}

// Round 8
// 2450.922 us; speedup vs baseline: 1.3402x; 1.3402x over previous
//
#include <hip/hip_runtime.h>
#include <math.h>

#define BATCH 8
#define NPTS 2048
#define KNN 20
#define BN_TOTAL (BATCH * NPTS)
#define EPSV 1e-5f
#define NSLOT 6                    // per-tile extracted candidates
#define NCAND (16 * NSLOT)         // 96 candidates per row

typedef __attribute__((ext_vector_type(8))) short short8v;   // 8 bf16
typedef __attribute__((ext_vector_type(4))) float floatx4;

// ---------------------------------------------------------------------------
// x2: per-row sum of squares
// ---------------------------------------------------------------------------
__global__ __launch_bounds__(256) void x2_kernel(const float* __restrict__ x, int C, int ldx,
                                                 float* __restrict__ x2) {
    int i = blockIdx.x * 256 + threadIdx.x;
    if (i >= BN_TOTAL) return;
    const float* xr = x + (size_t)i * ldx;
    float s = 0.f;
    if ((ldx & 3) == 0 && (C & 3) == 0) {
        const float4* xr4 = (const float4*)xr;
        for (int c = 0; c < (C >> 2); ++c) {
            float4 v = xr4[c];
            s = fmaf(v.x, v.x, s); s = fmaf(v.y, v.y, s);
            s = fmaf(v.z, v.z, s); s = fmaf(v.w, v.w, s);
        }
    } else {
        for (int c = 0; c < C; ++c) s = fmaf(xr[c], xr[c], s);
    }
    x2[i] = s;
}

__global__ __launch_bounds__(256) void zero_flags(int* __restrict__ flags) {
    int i = blockIdx.x * 256 + threadIdx.x;
    if (i < BN_TOTAL) flags[i] = 0;
}

// ---------------------------------------------------------------------------
// dtop6: round-4 dist GEMM (identical fp32 accumulation order) + per-(row,
// 128-col tile) top-6 extraction in registers. No S matrix is materialized.
// cand[row][jt*6+slot] = (negdist, j), priority order (val desc, j asc).
// ---------------------------------------------------------------------------
template <int C, int LDX>
__global__ __launch_bounds__(256) void dtop6(const float* __restrict__ x,
                                             const float* __restrict__ x2,
                                             float2* __restrict__ cand) {
    constexpr int KT = (C + 15) / 16;
    __shared__ float As[16][132];
    __shared__ float Bs[16][132];
    int b = blockIdx.z;
    int jt = blockIdx.y;
    int i0 = blockIdx.x * 128, j0 = jt * 128;
    const float* xb = x + (size_t)b * NPTS * LDX;
    int tid = threadIdx.x;
    int tm = tid >> 4, tn = tid & 15;

    float acc[8][8] = {};
    for (int kt = 0; kt < KT; ++kt) {
        int k0 = kt << 4;
#pragma unroll
        for (int s = tid; s < 512; s += 256) {
            int r = s >> 2, c4 = s & 3;
            int kk = k0 + c4 * 4;
            float va[4], vb[4];
            if (kk + 3 < C && (LDX & 3) == 0) {
                float4 a = *(const float4*)&xb[(size_t)(i0 + r) * LDX + kk];
                float4 bv = *(const float4*)&xb[(size_t)(j0 + r) * LDX + kk];
                va[0] = a.x; va[1] = a.y; va[2] = a.z; va[3] = a.w;
                vb[0] = bv.x; vb[1] = bv.y; vb[2] = bv.z; vb[3] = bv.w;
            } else {
#pragma unroll
                for (int u = 0; u < 4; ++u) {
                    int k = kk + u;
                    va[u] = (k < C) ? xb[(size_t)(i0 + r) * LDX + k] : 0.f;
                    vb[u] = (k < C) ? xb[(size_t)(j0 + r) * LDX + k] : 0.f;
                }
            }
#pragma unroll
            for (int u = 0; u < 4; ++u) {
                As[c4 * 4 + u][r] = va[u];
                Bs[c4 * 4 + u][r] = vb[u];
            }
        }
        __syncthreads();
#pragma unroll
        for (int k = 0; k < 16; ++k) {
            float4 a0 = *(const float4*)&As[k][tm * 8];
            float4 a1 = *(const float4*)&As[k][tm * 8 + 4];
            float4 c0 = *(const float4*)&Bs[k][tn * 8];
            float4 c1 = *(const float4*)&Bs[k][tn * 8 + 4];
            float av[8] = {a0.x, a0.y, a0.z, a0.w, a1.x, a1.y, a1.z, a1.w};
            float bv[8] = {c0.x, c0.y, c0.z, c0.w, c1.x, c1.y, c1.z, c1.w};
#pragma unroll
            for (int mi = 0; mi < 8; ++mi)
#pragma unroll
                for (int ni = 0; ni < 8; ++ni)
                    acc[mi][ni] = fmaf(av[mi], bv[ni], acc[mi][ni]);
        }
        __syncthreads();
    }

    // neg-dist transform (identical arithmetic to prior rounds)
    const float* x2b = x2 + (size_t)b * NPTS;
    float xj[8];
#pragma unroll
    for (int u = 0; u < 8; ++u) xj[u] = x2b[j0 + tn * 8 + u];
#pragma unroll
    for (int mi = 0; mi < 8; ++mi) {
        float xi = x2b[i0 + tm * 8 + mi];
#pragma unroll
        for (int ni = 0; ni < 8; ++ni)
            acc[mi][ni] = 2.f * acc[mi][ni] - xi - xj[ni];
    }

    // per-row top-6 of this 128-col tile (16 lanes per row, in registers)
#pragma unroll
    for (int mi = 0; mi < 8; ++mi) {
        float lv = acc[mi][0]; int lu = 0;
#pragma unroll
        for (int u = 1; u < 8; ++u)
            if (acc[mi][u] > lv) { lv = acc[mi][u]; lu = u; }
        int lj = j0 + tn * 8 + lu;
        float wv = 0.f; int wj = 0;
#pragma unroll 1
        for (int it = 0; it < NSLOT; ++it) {
            float bv = lv; int bj = lj;
#pragma unroll
            for (int d = 1; d < 16; d <<= 1) {
                float ov = __shfl_xor(bv, d);
                int oj = __shfl_xor(bj, d);
                if (ov > bv || (ov == bv && oj < bj)) { bv = ov; bj = oj; }
            }
            if (tn == it) { wv = bv; wj = bj; }
            if (bj == lj) {         // owner consumes winner, rescans
#pragma unroll
                for (int u = 0; u < 8; ++u)
                    acc[mi][u] = (j0 + tn * 8 + u == bj) ? -INFINITY : acc[mi][u];
                lv = acc[mi][0]; lu = 0;
#pragma unroll
                for (int u = 1; u < 8; ++u)
                    if (acc[mi][u] > lv) { lv = acc[mi][u]; lu = u; }
                lj = j0 + tn * 8 + lu;
            }
        }
        if (tn < NSLOT)
            cand[((size_t)(b << 11) + i0 + tm * 8 + mi) * NCAND + jt * NSLOT + tn] =
                make_float2(wv, __int_as_float(wj));
    }
}

// ---------------------------------------------------------------------------
// ktop96: one wave per row; exact top-20 of the 96 candidates. Flags rows
// where any tile's 6th-best beats the provisional 20th (superset violated).
// ---------------------------------------------------------------------------
__global__ __launch_bounds__(256) void ktop96(const float2* __restrict__ cand,
                                              int* __restrict__ idx_out,
                                              int* __restrict__ flags) {
    int lane = threadIdx.x & 63, w = threadIdx.x >> 6;
    int row = blockIdx.x * 4 + w;
    const float2* cr = cand + (size_t)row * NCAND;
    float v0, v1; int j0_, j1_;
    { float2 c = cr[lane]; v0 = c.x; j0_ = __float_as_int(c.y); }
    if (lane < NCAND - 64) {
        float2 c = cr[64 + lane]; v1 = c.x; j1_ = __float_as_int(c.y);
    } else { v1 = -INFINITY; j1_ = 0x7fffffff; }
    float ov0 = v0, ov1 = v1; int oj0 = j0_, oj1 = j1_;

    bool p1 = (v1 > v0) || (v1 == v0 && j1_ < j0_);
    float lv = p1 ? v1 : v0; int lj = p1 ? j1_ : j0_;

    int sel = 0;
    float kv = 0.f; int kj = 0;
#pragma unroll 1
    for (int it = 0; it < KNN; ++it) {
        float bv = lv; int bj = lj;
#pragma unroll
        for (int d = 1; d < 64; d <<= 1) {
            float ovv = __shfl_xor(bv, d);
            int ojj = __shfl_xor(bj, d);
            if (ovv > bv || (ovv == bv && ojj < bj)) { bv = ovv; bj = ojj; }
        }
        if (lane == it) sel = bj;
        if (it == KNN - 1) { kv = bv; kj = bj; }
        if (j0_ == bj) { v0 = -INFINITY; j0_ = 0x7fffffff; }
        if (j1_ == bj) { v1 = -INFINITY; j1_ = 0x7fffffff; }
        bool q1 = (v1 > v0) || (v1 == v0 && j1_ < j0_);
        lv = q1 ? v1 : v0; lj = q1 ? j1_ : j0_;
    }

    // flag test: candidate index c with c % 6 == 5 is a tile's 6th-best
    bool f0 = ((lane % NSLOT) == (NSLOT - 1)) &&
              (ov0 > kv || (ov0 == kv && oj0 < kj));
    bool f1 = (lane < NCAND - 64) && (((64 + lane) % NSLOT) == (NSLOT - 1)) &&
              (ov1 > kv || (ov1 == kv && oj1 < kj));
    unsigned long long ball = __ballot(f0 || f1);
    if (ball == 0ull) {
        if (lane < KNN) idx_out[(size_t)row * KNN + lane] = sel;
        if (lane == 0) flags[row] = 0;
    } else if (lane == 0) {
        flags[row] = 1;
    }
}

// ---------------------------------------------------------------------------
// knn_exact: fallback for flagged rows — recompute the full 2048 distances
// with the bitwise-identical ascending-k fmaf chain, then exact wave top-20.
// ---------------------------------------------------------------------------
__global__ __launch_bounds__(256) void knn_exact(const float* __restrict__ x,
                                                 const float* __restrict__ x2,
                                                 int C, int ldx,
                                                 const int* __restrict__ flags,
                                                 int* __restrict__ idx_out) {
    __shared__ float sxi[132];
    __shared__ float sd[NPTS];
    int tid = threadIdx.x;
    for (int row = blockIdx.x; row < BN_TOTAL; row += gridDim.x) {
        if (flags[row] == 0) continue;
        int b = row >> 11, i = row & 2047;
        const float* xb = x + (size_t)b * NPTS * ldx;
        for (int k = tid; k < C; k += 256) sxi[k] = xb[(size_t)i * ldx + k];
        __syncthreads();
        float x2i = x2[row];
        const float* x2b = x2 + (b << 11);
        for (int j = tid; j < NPTS; j += 256) {
            const float* xj = xb + (size_t)j * ldx;
            float dot = 0.f;
            for (int k = 0; k < C; ++k) dot = fmaf(sxi[k], xj[k], dot);
            sd[j] = 2.f * dot - x2i - x2b[j];
        }
        __syncthreads();
        if (tid < 64) {
            int lane = tid;
            float v[32];
            float lm = -INFINITY; int li = 0;
#pragma unroll
            for (int q = 0; q < 32; ++q) {
                v[q] = sd[lane * 32 + q];
                if (v[q] > lm) { lm = v[q]; li = q; }
            }
            int sel = 0;
#pragma unroll 1
            for (int it = 0; it < KNN; ++it) {
                float bv = lm; int bi = (lane << 5) | li;
#pragma unroll
                for (int d = 1; d < 64; d <<= 1) {
                    float ovv = __shfl_xor(bv, d);
                    int oii = __shfl_xor(bi, d);
                    if (ovv > bv || (ovv == bv && oii < bi)) { bv = ovv; bi = oii; }
                }
                if (lane == it) sel = bi;
                if ((bi >> 5) == lane) {
                    int r = bi & 31;
#pragma unroll
                    for (int q = 0; q < 32; ++q)
                        if (q == r) v[q] = -INFINITY;
                    lm = -INFINITY; li = 0;
#pragma unroll
                    for (int q = 0; q < 32; ++q)
                        if (v[q] > lm) { lm = v[q]; li = q; }
                }
            }
            if (lane < KNN) idx_out[(size_t)row * KNN + lane] = sel;
        }
        __syncthreads();
    }
}

// ---------------------------------------------------------------------------
// pq_gemm: PQ[bn][0..O)=x.Wp^T, PQ[bn][O..2O)=x.Wq^T as one GEMM (N=2O).
// ---------------------------------------------------------------------------
__global__ __launch_bounds__(256) void pq_gemm(const float* __restrict__ X, int C, int ldx,
                                               const float* __restrict__ W, int O,
                                               float* __restrict__ PQ) {
    __shared__ float As[32][68];
    __shared__ float Bs[32][68];
    int i0 = blockIdx.x * 64, j0 = blockIdx.y * 64;
    int tid = threadIdx.x;
    int tm = tid >> 4, tn = tid & 15;
    int N2 = 2 * O;

    float acc[4][4] = {};
    int KT = (C + 31) >> 5;
    for (int kt = 0; kt < KT; ++kt) {
        int k0 = kt << 5;
        for (int e = tid; e < 2048; e += 256) {
            int m = e >> 5, k = e & 31;
            int kk = k0 + k;
            As[k][m] = (kk < C) ? X[(size_t)(i0 + m) * ldx + kk] : 0.f;
            int o = j0 + m;
            float wv = 0.f;
            if (kk < C)
                wv = (o < O) ? W[(size_t)o * 2 * C + kk] : W[(size_t)(o - O) * 2 * C + C + kk];
            Bs[k][m] = wv;
        }
        __syncthreads();
#pragma unroll
        for (int k = 0; k < 32; ++k) {
            float4 a = *(const float4*)&As[k][tm * 4];
            float4 bb = *(const float4*)&Bs[k][tn * 4];
            float av[4] = {a.x, a.y, a.z, a.w};
            float bv[4] = {bb.x, bb.y, bb.z, bb.w};
#pragma unroll
            for (int mi = 0; mi < 4; ++mi)
#pragma unroll
                for (int ni = 0; ni < 4; ++ni)
                    acc[mi][ni] = fmaf(av[mi], bv[ni], acc[mi][ni]);
        }
        __syncthreads();
    }
#pragma unroll
    for (int mi = 0; mi < 4; ++mi) {
        float4 o;
        o.x = acc[mi][0]; o.y = acc[mi][1]; o.z = acc[mi][2]; o.w = acc[mi][3];
        *(float4*)&PQ[(size_t)(i0 + tm * 4 + mi) * N2 + j0 + tn * 4] = o;
    }
}

// ---------------------------------------------------------------------------
// gather-max + BN + LeakyReLU epilogue. 256/O rows per block, all lanes busy.
// ---------------------------------------------------------------------------
__global__ __launch_bounds__(256) void gmax_kernel(const float* __restrict__ PQ,
                                                   const int* __restrict__ idx, int O, int oshift,
                                                   const float* __restrict__ gamma,
                                                   const float* __restrict__ beta,
                                                   float* __restrict__ out, int ldo) {
    __shared__ int s_idx[4][KNN];
    int rpb = 256 >> oshift;                 // O in {64,128,256}
    int lr = threadIdx.x >> oshift;
    int o = threadIdx.x & (O - 1);
    int bn = blockIdx.x * rpb + lr;
    int b = bn >> 11;
    if (o < KNN) s_idx[lr][o] = idx[bn * KNN + o];
    __syncthreads();
    const float inv = 1.0f / sqrtf(1.0f + EPSV);
    int N2 = 2 * O;
    size_t brow = (size_t)(b << 11);
    float mx = -INFINITY, mn = INFINITY;
#pragma unroll
    for (int k = 0; k < KNN; ++k) {
        float v = PQ[(brow + s_idx[lr][k]) * N2 + o];
        mx = fmaxf(mx, v);
        mn = fminf(mn, v);
    }
    float pn = PQ[(size_t)bn * N2 + o];
    float qn = PQ[(size_t)bn * N2 + O + o];
    float sc = gamma[o] * inv;
    float m = (sc >= 0.f) ? mx : mn;
    float z = sc * (m - pn + qn) + beta[o];
    out[(size_t)bn * ldo + o] = (z >= 0.f) ? z : 0.2f * z;
}

// ---------------------------------------------------------------------------
// split_bf16: x -> (hi, lo) bf16 pair, RNE.
// ---------------------------------------------------------------------------
__device__ __forceinline__ unsigned short bf16_rne(float x) {
    union { float f; unsigned u; } cv; cv.f = x;
    unsigned r = (cv.u + 0x7fffu + ((cv.u >> 16) & 1u)) >> 16;
    return (unsigned short)r;
}
__global__ __launch_bounds__(256) void split_bf16_kernel(const float* __restrict__ in, int n4,
                                                         unsigned short* __restrict__ hi,
                                                         unsigned short* __restrict__ lo) {
    int i = blockIdx.x * 256 + threadIdx.x;
    if (i >= n4) return;
    float4 v = ((const float4*)in)[i];
    float vv[4] = {v.x, v.y, v.z, v.w};
    ushort4 h, l;
    unsigned short hh[4], ll[4];
#pragma unroll
    for (int u = 0; u < 4; ++u) {
        unsigned short hb = bf16_rne(vv[u]);
        union { unsigned u32; float f; } hf; hf.u32 = ((unsigned)hb) << 16;
        hh[u] = hb;
        ll[u] = bf16_rne(vv[u] - hf.f);
    }
    h.x = hh[0]; h.y = hh[1]; h.z = hh[2]; h.w = hh[3];
    l.x = ll[0]; l.y = ll[1]; l.z = ll[2]; l.w = ll[3];
    *(ushort4*)(hi + (size_t)i * 4) = h;
    *(ushort4*)(lo + (size_t)i * 4) = l;
}

// ---------------------------------------------------------------------------
// final MFMA GEMM: feat = lrelu(bn(X @ W5^T)) with split-bf16 (3 K-segments),
// fused partial max/sum over the 128 n-rows. 128x128 tile, BK=32, 4 waves.
// ---------------------------------------------------------------------------
__global__ __launch_bounds__(256) void final_mfma(const unsigned short* __restrict__ Xhi,
                                                  const unsigned short* __restrict__ Xlo,
                                                  const unsigned short* __restrict__ Whi,
                                                  const unsigned short* __restrict__ Wlo,
                                                  const float* __restrict__ g5,
                                                  const float* __restrict__ b5,
                                                  float* __restrict__ part) {
    __shared__ __align__(16) char As[128 * 64];
    __shared__ __align__(16) char Bs[128 * 64];
    __shared__ float sredM[2][128];
    __shared__ float sredS[2][128];

    int tid = threadIdx.x;
    int i0 = blockIdx.x * 128;
    int j0 = blockIdx.y * 128;
    int lane = tid & 63, w = tid >> 6;
    int wr = w >> 1, wc = w & 1;

    int rowA = tid >> 2, q = tid & 3;
    auto swz = [](int row, int qq) { return (row * 64 + qq * 16) ^ ((row & 7) << 4); };
    int wa0 = swz(rowA, q), wa1 = swz(rowA + 64, q);

    int fr = lane & 15, slot = lane >> 4;
    int aoff[4], boff[4];
#pragma unroll
    for (int m = 0; m < 4; ++m) {
        int ra = wr * 64 + m * 16 + fr;
        aoff[m] = (ra * 64 + slot * 16) ^ ((ra & 7) << 4);
        int rb = wc * 64 + m * 16 + fr;
        boff[m] = (rb * 64 + slot * 16) ^ ((rb & 7) << 4);
    }

    floatx4 acc[4][4];
#pragma unroll
    for (int m = 0; m < 4; ++m)
#pragma unroll
        for (int n = 0; n < 4; ++n)
            acc[m][n] = (floatx4){0.f, 0.f, 0.f, 0.f};

    uint4 ra0, ra1, rb0, rb1;
    auto prefetch = [&](int it) {
        int seg = it >> 4;
        int kk = (it & 15) * 32;
        const unsigned short* Ab = ((seg < 2) ? Xhi : Xlo) + (size_t)i0 * 512 + kk + q * 8;
        const unsigned short* Bb = ((seg == 1) ? Wlo : Whi) + (size_t)j0 * 512 + kk + q * 8;
        ra0 = *(const uint4*)(Ab + (size_t)rowA * 512);
        ra1 = *(const uint4*)(Ab + (size_t)(rowA + 64) * 512);
        rb0 = *(const uint4*)(Bb + (size_t)rowA * 512);
        rb1 = *(const uint4*)(Bb + (size_t)(rowA + 64) * 512);
    };

    prefetch(0);
    for (int it = 0; it < 48; ++it) {
        __syncthreads();
        *(uint4*)(As + wa0) = ra0;
        *(uint4*)(As + wa1) = ra1;
        *(uint4*)(Bs + wa0) = rb0;
        *(uint4*)(Bs + wa1) = rb1;
        __syncthreads();
        if (it < 47) prefetch(it + 1);
        short8v af[4], bf[4];
#pragma unroll
        for (int m = 0; m < 4; ++m) af[m] = *(const short8v*)(As + aoff[m]);
#pragma unroll
        for (int n = 0; n < 4; ++n) bf[n] = *(const short8v*)(Bs + boff[n]);
#pragma unroll
        for (int m = 0; m < 4; ++m)
#pragma unroll
            for (int n = 0; n < 4; ++n)
                acc[m][n] = __builtin_amdgcn_mfma_f32_16x16x32_bf16(af[m], bf[n], acc[m][n], 0, 0, 0);
    }

    const float inv = 1.0f / sqrtf(1.0f + EPSV);
#pragma unroll
    for (int n = 0; n < 4; ++n) {
        int o = j0 + wc * 64 + n * 16 + fr;
        float sc = g5[o] * inv;
        float bi = b5[o];
        float mx = -INFINITY, sm = 0.f;
#pragma unroll
        for (int m = 0; m < 4; ++m)
#pragma unroll
            for (int r = 0; r < 4; ++r) {
                float z = fmaf(sc, acc[m][n][r], bi);
                z = (z >= 0.f) ? z : 0.2f * z;
                mx = fmaxf(mx, z);
                sm += z;
            }
#pragma unroll
        for (int d = 16; d < 64; d <<= 1) {
            mx = fmaxf(mx, __shfl_xor(mx, d));
            sm += __shfl_xor(sm, d);
        }
        if (slot == 0) {
            sredM[wr][wc * 64 + n * 16 + fr] = mx;
            sredS[wr][wc * 64 + n * 16 + fr] = sm;
        }
    }
    __syncthreads();
    if (tid < 128) {
        float m = fmaxf(sredM[0][tid], sredM[1][tid]);
        float s = sredS[0][tid] + sredS[1][tid];
        int b = i0 >> 11, nt = (i0 >> 7) & 15;
        size_t base = (size_t)((b * 16 + nt) * 2) * 1024 + j0 + tid;
        part[base] = m;
        part[base + 1024] = s;
    }
}

__global__ __launch_bounds__(256) void freduce_kernel(const float* __restrict__ part,
                                                      float* __restrict__ out) {
    int t = blockIdx.x * 256 + threadIdx.x;
    if (t >= 8 * 1024) return;
    int b = t >> 10, o = t & 1023;
    float m = -INFINITY, s = 0.f;
#pragma unroll
    for (int nt = 0; nt < 16; ++nt) {
        size_t base = (size_t)((b * 16 + nt) * 2) * 1024 + o;
        m = fmaxf(m, part[base]);
        s += part[base + 1024];
    }
    out[b * 2048 + o] = m;
    out[b * 2048 + 1024 + o] = s * (1.0f / 2048.0f);
}

// ---------------------------------------------------------------------------
extern "C" void kernel_launch(void* const* d_in, const int* in_sizes, int n_in,
                              void* d_out, int out_size, void* d_ws, size_t ws_size,
                              hipStream_t stream) {
    const float* points = (const float*)d_in[0];
    const float* W1 = (const float*)d_in[1];
    const float* W2 = (const float*)d_in[2];
    const float* W3 = (const float*)d_in[3];
    const float* W4 = (const float*)d_in[4];
    const float* W5 = (const float*)d_in[5];
    const float* g1 = (const float*)d_in[6];
    const float* b1 = (const float*)d_in[7];
    const float* g2 = (const float*)d_in[8];
    const float* b2 = (const float*)d_in[9];
    const float* g3 = (const float*)d_in[10];
    const float* b3 = (const float*)d_in[11];
    const float* g4 = (const float*)d_in[12];
    const float* b4 = (const float*)d_in[13];
    const float* g5 = (const float*)d_in[14];
    const float* b5 = (const float*)d_in[15];
    float* out = (float*)d_out;

    const size_t f_xcat = (size_t)BN_TOTAL * 512;            // 8.4M floats
    const size_t f_w5 = (size_t)1024 * 512;
    const size_t f_union = (size_t)BN_TOTAL * 320 * 2;       // SPQ | cand | bf16
    const size_t f_x2 = BN_TOTAL;
    const size_t f_idx = (size_t)BN_TOTAL * KNN;             // ints
    const size_t f_part = (size_t)8 * 16 * 2 * 1024;

    float* xcat = (float*)d_ws;
    float* U = xcat + f_xcat;               // union: SPQ | cand | bf16 buffers
    float* SPQ = U;
    float2* cand = (float2*)U;
    unsigned short* Xhi = (unsigned short*)U;
    unsigned short* Xlo = Xhi + f_xcat;
    unsigned short* Whi = Xlo + f_xcat;
    unsigned short* Wlo = Whi + f_w5;
    float* x2 = U + f_union;
    int* idx = (int*)(x2 + f_x2);
    float* part = (float*)(idx + f_idx);
    int* flags = (int*)(part + f_part);

    // ---- layer 1 (C=3 -> O=64)
    x2_kernel<<<64, 256, 0, stream>>>(points, 3, 3, x2);
    zero_flags<<<64, 256, 0, stream>>>(flags);
    dtop6<3, 3><<<dim3(16, 16, 8), 256, 0, stream>>>(points, x2, cand);
    ktop96<<<BN_TOTAL / 4, 256, 0, stream>>>(cand, idx, flags);
    knn_exact<<<256, 256, 0, stream>>>(points, x2, 3, 3, flags, idx);
    pq_gemm<<<dim3(256, 2), 256, 0, stream>>>(points, 3, 3, W1, 64, SPQ);
    gmax_kernel<<<BN_TOTAL / 4, 256, 0, stream>>>(SPQ, idx, 64, 6, g1, b1, xcat + 0, 512);

    // ---- layer 2 (C=64 -> O=64)
    x2_kernel<<<64, 256, 0, stream>>>(xcat + 0, 64, 512, x2);
    zero_flags<<<64, 256, 0, stream>>>(flags);
    dtop6<64, 512><<<dim3(16, 16, 8), 256, 0, stream>>>(xcat + 0, x2, cand);
    ktop96<<<BN_TOTAL / 4, 256, 0, stream>>>(cand, idx, flags);
    knn_exact<<<256, 256, 0, stream>>>(xcat + 0, x2, 64, 512, flags, idx);
    pq_gemm<<<dim3(256, 2), 256, 0, stream>>>(xcat + 0, 64, 512, W2, 64, SPQ);
    gmax_kernel<<<BN_TOTAL / 4, 256, 0, stream>>>(SPQ, idx, 64, 6, g2, b2, xcat + 64, 512);

    // ---- layer 3 (C=64 -> O=128)
    x2_kernel<<<64, 256, 0, stream>>>(xcat + 64, 64, 512, x2);
    zero_flags<<<64, 256, 0, stream>>>(flags);
    dtop6<64, 512><<<dim3(16, 16, 8), 256, 0, stream>>>(xcat + 64, x2, cand);
    ktop96<<<BN_TOTAL / 4, 256, 0, stream>>>(cand, idx, flags);
    knn_exact<<<256, 256, 0, stream>>>(xcat + 64, x2, 64, 512, flags, idx);
    pq_gemm<<<dim3(256, 4), 256, 0, stream>>>(xcat + 64, 64, 512, W3, 128, SPQ);
    gmax_kernel<<<BN_TOTAL / 2, 256, 0, stream>>>(SPQ, idx, 128, 7, g3, b3, xcat + 128, 512);

    // ---- layer 4 (C=128 -> O=256)
    x2_kernel<<<64, 256, 0, stream>>>(xcat + 128, 128, 512, x2);
    zero_flags<<<64, 256, 0, stream>>>(flags);
    dtop6<128, 512><<<dim3(16, 16, 8), 256, 0, stream>>>(xcat + 128, x2, cand);
    ktop96<<<BN_TOTAL / 4, 256, 0, stream>>>(cand, idx, flags);
    knn_exact<<<256, 256, 0, stream>>>(xcat + 128, x2, 128, 512, flags, idx);
    pq_gemm<<<dim3(256, 8), 256, 0, stream>>>(xcat + 128, 128, 512, W4, 256, SPQ);
    gmax_kernel<<<BN_TOTAL, 256, 0, stream>>>(SPQ, idx, 256, 8, g4, b4, xcat + 256, 512);

    // ---- final layer
    split_bf16_kernel<<<(int)((f_xcat / 4 + 255) / 256), 256, 0, stream>>>(xcat, (int)(f_xcat / 4), Xhi, Xlo);
    split_bf16_kernel<<<(int)((f_w5 / 4 + 255) / 256), 256, 0, stream>>>(W5, (int)(f_w5 / 4), Whi, Wlo);
    final_mfma<<<dim3(BN_TOTAL / 128, 1024 / 128), 256, 0, stream>>>(Xhi, Xlo, Whi, Wlo, g5, b5, part);
    freduce_kernel<<<(8 * 1024 + 255) / 256, 256, 0, stream>>>(part, out);
}

// Round 10
// 1235.738 us; speedup vs baseline: 2.6580x; 1.9834x over previous
//
#include <hip/hip_runtime.h>
#include <math.h>

#define BATCH 8
#define NPTS 2048
#define KNN 20
#define BN_TOTAL (BATCH * NPTS)
#define EPSV 1e-5f

typedef __attribute__((ext_vector_type(8))) short short8v;   // 8 bf16
typedef __attribute__((ext_vector_type(4))) float floatx4;

// ---------------------------------------------------------------------------
// x2: per-row sum of squares
// ---------------------------------------------------------------------------
__global__ __launch_bounds__(256) void x2_kernel(const float* __restrict__ x, int C, int ldx,
                                                 float* __restrict__ x2) {
    int i = blockIdx.x * 256 + threadIdx.x;
    if (i >= BN_TOTAL) return;
    const float* xr = x + (size_t)i * ldx;
    float s = 0.f;
    if ((ldx & 3) == 0 && (C & 3) == 0) {
        const float4* xr4 = (const float4*)xr;
        for (int c = 0; c < (C >> 2); ++c) {
            float4 v = xr4[c];
            s = fmaf(v.x, v.x, s); s = fmaf(v.y, v.y, s);
            s = fmaf(v.z, v.z, s); s = fmaf(v.w, v.w, s);
        }
    } else {
        for (int c = 0; c < C; ++c) s = fmaf(xr[c], xr[c], s);
    }
    x2[i] = s;
}

// ---------------------------------------------------------------------------
// dist: tiled GEMM, neg_dist S[z*2048+i][j] = 2*dot(xi,xj) - x2i - x2j.
// 128x128 tile, BK=16, 256 thr, 8x8 micro-tile. (verbatim round-4 kernel)
// ---------------------------------------------------------------------------
__global__ __launch_bounds__(256) void dist_kernel(const float* __restrict__ x,
                                                   const float* __restrict__ x2,
                                                   int C, int ldx, int b0,
                                                   float* __restrict__ S) {
    __shared__ float As[16][132];
    __shared__ float Bs[16][132];
    int z = blockIdx.z;
    int b = b0 + z;
    int i0 = blockIdx.x * 128, j0 = blockIdx.y * 128;
    const float* xb = x + (size_t)b * NPTS * ldx;
    int tid = threadIdx.x;
    int tm = tid >> 4, tn = tid & 15;

    float acc[8][8] = {};
    int KT = (C + 15) >> 4;
    for (int kt = 0; kt < KT; ++kt) {
        int k0 = kt << 4;
#pragma unroll
        for (int s = tid; s < 512; s += 256) {
            int r = s >> 2, c4 = s & 3;
            int kk = k0 + c4 * 4;
            float va[4], vb[4];
            if (kk + 3 < C && (ldx & 3) == 0) {
                float4 a = *(const float4*)&xb[(size_t)(i0 + r) * ldx + kk];
                float4 bv = *(const float4*)&xb[(size_t)(j0 + r) * ldx + kk];
                va[0] = a.x; va[1] = a.y; va[2] = a.z; va[3] = a.w;
                vb[0] = bv.x; vb[1] = bv.y; vb[2] = bv.z; vb[3] = bv.w;
            } else {
#pragma unroll
                for (int u = 0; u < 4; ++u) {
                    int k = kk + u;
                    va[u] = (k < C) ? xb[(size_t)(i0 + r) * ldx + k] : 0.f;
                    vb[u] = (k < C) ? xb[(size_t)(j0 + r) * ldx + k] : 0.f;
                }
            }
#pragma unroll
            for (int u = 0; u < 4; ++u) {
                As[c4 * 4 + u][r] = va[u];
                Bs[c4 * 4 + u][r] = vb[u];
            }
        }
        __syncthreads();
#pragma unroll
        for (int k = 0; k < 16; ++k) {
            float4 a0 = *(const float4*)&As[k][tm * 8];
            float4 a1 = *(const float4*)&As[k][tm * 8 + 4];
            float4 c0 = *(const float4*)&Bs[k][tn * 8];
            float4 c1 = *(const float4*)&Bs[k][tn * 8 + 4];
            float av[8] = {a0.x, a0.y, a0.z, a0.w, a1.x, a1.y, a1.z, a1.w};
            float bv[8] = {c0.x, c0.y, c0.z, c0.w, c1.x, c1.y, c1.z, c1.w};
#pragma unroll
            for (int mi = 0; mi < 8; ++mi)
#pragma unroll
                for (int ni = 0; ni < 8; ++ni)
                    acc[mi][ni] = fmaf(av[mi], bv[ni], acc[mi][ni]);
        }
        __syncthreads();
    }

    const float* x2b = x2 + (size_t)b * NPTS;
    float xj[8];
#pragma unroll
    for (int u = 0; u < 8; ++u) xj[u] = x2b[j0 + tn * 8 + u];
#pragma unroll
    for (int mi = 0; mi < 8; ++mi) {
        float xi = x2b[i0 + tm * 8 + mi];
        float4 o0, o1;
        o0.x = 2.f * acc[mi][0] - xi - xj[0];
        o0.y = 2.f * acc[mi][1] - xi - xj[1];
        o0.z = 2.f * acc[mi][2] - xi - xj[2];
        o0.w = 2.f * acc[mi][3] - xi - xj[3];
        o1.x = 2.f * acc[mi][4] - xi - xj[4];
        o1.y = 2.f * acc[mi][5] - xi - xj[5];
        o1.z = 2.f * acc[mi][6] - xi - xj[6];
        o1.w = 2.f * acc[mi][7] - xi - xj[7];
        size_t rowp = ((size_t)z * NPTS + i0 + tm * 8 + mi) * NPTS + j0 + tn * 8;
        *(float4*)&S[rowp] = o0;
        *(float4*)&S[rowp + 4] = o1;
    }
}

// ---------------------------------------------------------------------------
// topk: one wave per row; 32 values/lane in registers; 20 shfl-argmax iters.
// (verbatim round-4 kernel)
// ---------------------------------------------------------------------------
__global__ __launch_bounds__(256) void topk_kernel(const float* __restrict__ S, int b0,
                                                   int* __restrict__ idx_out) {
    int lane = threadIdx.x & 63, w = threadIdx.x >> 6;
    int row = blockIdx.x * 4 + w;
    const float4* S4 = (const float4*)(S + (size_t)row * NPTS);

    float v[32];
    float lm = -INFINITY; int li = 0;
#pragma unroll
    for (int r4 = 0; r4 < 8; ++r4) {
        float4 f = S4[lane * 8 + r4];
        v[r4 * 4 + 0] = f.x; v[r4 * 4 + 1] = f.y;
        v[r4 * 4 + 2] = f.z; v[r4 * 4 + 3] = f.w;
    }
#pragma unroll
    for (int q = 0; q < 32; ++q)
        if (v[q] > lm) { lm = v[q]; li = q; }

    int sel = 0;
#pragma unroll 1
    for (int it = 0; it < KNN; ++it) {
        float bv = lm;
        int bi = (lane << 5) | li;
#pragma unroll
        for (int d = 1; d < 64; d <<= 1) {
            float ov = __shfl_xor(bv, d);
            int oi = __shfl_xor(bi, d);
            if (ov > bv || (ov == bv && oi < bi)) { bv = ov; bi = oi; }
        }
        if (lane == it) sel = bi;
        if ((bi >> 5) == lane) {
            int r = bi & 31;
#pragma unroll
            for (int q = 0; q < 32; ++q)
                if (q == r) v[q] = -INFINITY;
            lm = -INFINITY; li = 0;
#pragma unroll
            for (int q = 0; q < 32; ++q)
                if (v[q] > lm) { lm = v[q]; li = q; }
        }
    }
    int z = row >> 11, i = row & 2047;
    int bn = (b0 + z) * NPTS + i;
    if (lane < KNN) idx_out[bn * KNN + lane] = sel;
}

// ---------------------------------------------------------------------------
// pq_gemm: PQ[bn][0..O)=x.Wp^T, PQ[bn][O..2O)=x.Wq^T as one GEMM (N=2O).
// ---------------------------------------------------------------------------
__global__ __launch_bounds__(256) void pq_gemm(const float* __restrict__ X, int C, int ldx,
                                               const float* __restrict__ W, int O,
                                               float* __restrict__ PQ) {
    __shared__ float As[32][68];
    __shared__ float Bs[32][68];
    int i0 = blockIdx.x * 64, j0 = blockIdx.y * 64;
    int tid = threadIdx.x;
    int tm = tid >> 4, tn = tid & 15;
    int N2 = 2 * O;

    float acc[4][4] = {};
    int KT = (C + 31) >> 5;
    for (int kt = 0; kt < KT; ++kt) {
        int k0 = kt << 5;
        for (int e = tid; e < 2048; e += 256) {
            int m = e >> 5, k = e & 31;
            int kk = k0 + k;
            As[k][m] = (kk < C) ? X[(size_t)(i0 + m) * ldx + kk] : 0.f;
            int o = j0 + m;
            float wv = 0.f;
            if (kk < C)
                wv = (o < O) ? W[(size_t)o * 2 * C + kk] : W[(size_t)(o - O) * 2 * C + C + kk];
            Bs[k][m] = wv;
        }
        __syncthreads();
#pragma unroll
        for (int k = 0; k < 32; ++k) {
            float4 a = *(const float4*)&As[k][tm * 4];
            float4 bb = *(const float4*)&Bs[k][tn * 4];
            float av[4] = {a.x, a.y, a.z, a.w};
            float bv[4] = {bb.x, bb.y, bb.z, bb.w};
#pragma unroll
            for (int mi = 0; mi < 4; ++mi)
#pragma unroll
                for (int ni = 0; ni < 4; ++ni)
                    acc[mi][ni] = fmaf(av[mi], bv[ni], acc[mi][ni]);
        }
        __syncthreads();
    }
#pragma unroll
    for (int mi = 0; mi < 4; ++mi) {
        float4 o;
        o.x = acc[mi][0]; o.y = acc[mi][1]; o.z = acc[mi][2]; o.w = acc[mi][3];
        *(float4*)&PQ[(size_t)(i0 + tm * 4 + mi) * N2 + j0 + tn * 4] = o;
    }
}

// ---------------------------------------------------------------------------
// gather-max + BN + LeakyReLU epilogue. 256/O rows per block, all lanes busy.
// ---------------------------------------------------------------------------
__global__ __launch_bounds__(256) void gmax_kernel(const float* __restrict__ PQ,
                                                   const int* __restrict__ idx, int O, int oshift,
                                                   const float* __restrict__ gamma,
                                                   const float* __restrict__ beta,
                                                   float* __restrict__ out, int ldo) {
    __shared__ int s_idx[4][KNN];
    int rpb = 256 >> oshift;                 // O in {64,128,256}
    int lr = threadIdx.x >> oshift;
    int o = threadIdx.x & (O - 1);
    int bn = blockIdx.x * rpb + lr;
    int b = bn >> 11;
    if (o < KNN) s_idx[lr][o] = idx[bn * KNN + o];
    __syncthreads();
    const float inv = 1.0f / sqrtf(1.0f + EPSV);
    int N2 = 2 * O;
    size_t brow = (size_t)(b << 11);
    float mx = -INFINITY, mn = INFINITY;
#pragma unroll
    for (int k = 0; k < KNN; ++k) {
        float v = PQ[(brow + s_idx[lr][k]) * N2 + o];
        mx = fmaxf(mx, v);
        mn = fminf(mn, v);
    }
    float pn = PQ[(size_t)bn * N2 + o];
    float qn = PQ[(size_t)bn * N2 + O + o];
    float sc = gamma[o] * inv;
    float m = (sc >= 0.f) ? mx : mn;
    float z = sc * (m - pn + qn) + beta[o];
    out[(size_t)bn * ldo + o] = (z >= 0.f) ? z : 0.2f * z;
}

// ---------------------------------------------------------------------------
// split_bf16: x -> (hi, lo) bf16 pair, RNE. hi+lo reproduces x to ~2^-16 rel.
// ---------------------------------------------------------------------------
__device__ __forceinline__ unsigned short bf16_rne(float x) {
    union { float f; unsigned u; } cv; cv.f = x;
    unsigned r = (cv.u + 0x7fffu + ((cv.u >> 16) & 1u)) >> 16;
    return (unsigned short)r;
}
__global__ __launch_bounds__(256) void split_bf16_kernel(const float* __restrict__ in, int n4,
                                                         unsigned short* __restrict__ hi,
                                                         unsigned short* __restrict__ lo) {
    int i = blockIdx.x * 256 + threadIdx.x;
    if (i >= n4) return;
    float4 v = ((const float4*)in)[i];
    float vv[4] = {v.x, v.y, v.z, v.w};
    ushort4 h, l;
    unsigned short hh[4], ll[4];
#pragma unroll
    for (int u = 0; u < 4; ++u) {
        unsigned short hb = bf16_rne(vv[u]);
        union { unsigned u32; float f; } hf; hf.u32 = ((unsigned)hb) << 16;
        hh[u] = hb;
        ll[u] = bf16_rne(vv[u] - hf.f);
    }
    h.x = hh[0]; h.y = hh[1]; h.z = hh[2]; h.w = hh[3];
    l.x = ll[0]; l.y = ll[1]; l.z = ll[2]; l.w = ll[3];
    *(ushort4*)(hi + (size_t)i * 4) = h;
    *(ushort4*)(lo + (size_t)i * 4) = l;
}

// ---------------------------------------------------------------------------
// final MFMA GEMM: feat = lrelu(bn(X @ W5^T)) with split-bf16 (3 K-segments:
// Xhi.Whi + Xhi.Wlo + Xlo.Whi), fused partial max/sum over the 128 n-rows.
// 128x128 tile, BK=32, 4 waves (2x2), each wave 4x4 frags of 16x16x32.
// ---------------------------------------------------------------------------
__global__ __launch_bounds__(256) void final_mfma(const unsigned short* __restrict__ Xhi,
                                                  const unsigned short* __restrict__ Xlo,
                                                  const unsigned short* __restrict__ Whi,
                                                  const unsigned short* __restrict__ Wlo,
                                                  const float* __restrict__ g5,
                                                  const float* __restrict__ b5,
                                                  float* __restrict__ part) {
    __shared__ __align__(16) char As[128 * 64];   // [row][32 bf16] swizzled
    __shared__ __align__(16) char Bs[128 * 64];
    __shared__ float sredM[2][128];
    __shared__ float sredS[2][128];

    int tid = threadIdx.x;
    int i0 = blockIdx.x * 128;
    int j0 = blockIdx.y * 128;
    int lane = tid & 63, w = tid >> 6;
    int wr = w >> 1, wc = w & 1;

    // staging assignment: thread -> (row, 16B-quarter), two rows apart 64
    int rowA = tid >> 2, q = tid & 3;
    auto swz = [](int row, int qq) { return (row * 64 + qq * 16) ^ ((row & 7) << 4); };
    int wa0 = swz(rowA, q), wa1 = swz(rowA + 64, q);

    // fragment LDS byte offsets (swizzled)
    int fr = lane & 15, slot = lane >> 4;
    int aoff[4], boff[4];
#pragma unroll
    for (int m = 0; m < 4; ++m) {
        int ra = wr * 64 + m * 16 + fr;
        aoff[m] = (ra * 64 + slot * 16) ^ ((ra & 7) << 4);
        int rb = wc * 64 + m * 16 + fr;
        boff[m] = (rb * 64 + slot * 16) ^ ((rb & 7) << 4);
    }

    floatx4 acc[4][4];
#pragma unroll
    for (int m = 0; m < 4; ++m)
#pragma unroll
        for (int n = 0; n < 4; ++n)
            acc[m][n] = (floatx4){0.f, 0.f, 0.f, 0.f};

    uint4 ra0, ra1, rb0, rb1;
    auto prefetch = [&](int it) {
        int seg = it >> 4;
        int kk = (it & 15) * 32;
        const unsigned short* Ab = ((seg < 2) ? Xhi : Xlo) + (size_t)i0 * 512 + kk + q * 8;
        const unsigned short* Bb = ((seg == 1) ? Wlo : Whi) + (size_t)j0 * 512 + kk + q * 8;
        ra0 = *(const uint4*)(Ab + (size_t)rowA * 512);
        ra1 = *(const uint4*)(Ab + (size_t)(rowA + 64) * 512);
        rb0 = *(const uint4*)(Bb + (size_t)rowA * 512);
        rb1 = *(const uint4*)(Bb + (size_t)(rowA + 64) * 512);
    };

    prefetch(0);
    for (int it = 0; it < 48; ++it) {
        __syncthreads();
        *(uint4*)(As + wa0) = ra0;
        *(uint4*)(As + wa1) = ra1;
        *(uint4*)(Bs + wa0) = rb0;
        *(uint4*)(Bs + wa1) = rb1;
        __syncthreads();
        if (it < 47) prefetch(it + 1);
        short8v af[4], bf[4];
#pragma unroll
        for (int m = 0; m < 4; ++m) af[m] = *(const short8v*)(As + aoff[m]);
#pragma unroll
        for (int n = 0; n < 4; ++n) bf[n] = *(const short8v*)(Bs + boff[n]);
#pragma unroll
        for (int m = 0; m < 4; ++m)
#pragma unroll
            for (int n = 0; n < 4; ++n)
                acc[m][n] = __builtin_amdgcn_mfma_f32_16x16x32_bf16(af[m], bf[n], acc[m][n], 0, 0, 0);
    }

    // epilogue: BN + lrelu + per-column (max,sum) over this block's 128 rows
    const float inv = 1.0f / sqrtf(1.0f + EPSV);
#pragma unroll
    for (int n = 0; n < 4; ++n) {
        int o = j0 + wc * 64 + n * 16 + fr;
        float sc = g5[o] * inv;
        float bi = b5[o];
        float mx = -INFINITY, sm = 0.f;
#pragma unroll
        for (int m = 0; m < 4; ++m)
#pragma unroll
            for (int r = 0; r < 4; ++r) {
                float z = fmaf(sc, acc[m][n][r], bi);
                z = (z >= 0.f) ? z : 0.2f * z;
                mx = fmaxf(mx, z);
                sm += z;
            }
#pragma unroll
        for (int d = 16; d < 64; d <<= 1) {
            mx = fmaxf(mx, __shfl_xor(mx, d));
            sm += __shfl_xor(sm, d);
        }
        if (slot == 0) {
            sredM[wr][wc * 64 + n * 16 + fr] = mx;
            sredS[wr][wc * 64 + n * 16 + fr] = sm;
        }
    }
    __syncthreads();
    if (tid < 128) {
        float m = fmaxf(sredM[0][tid], sredM[1][tid]);
        float s = sredS[0][tid] + sredS[1][tid];
        int b = i0 >> 11, nt = (i0 >> 7) & 15;
        size_t base = (size_t)((b * 16 + nt) * 2) * 1024 + j0 + tid;
        part[base] = m;
        part[base + 1024] = s;
    }
}

__global__ __launch_bounds__(256) void freduce_kernel(const float* __restrict__ part,
                                                      float* __restrict__ out) {
    int t = blockIdx.x * 256 + threadIdx.x;
    if (t >= 8 * 1024) return;
    int b = t >> 10, o = t & 1023;
    float m = -INFINITY, s = 0.f;
#pragma unroll
    for (int nt = 0; nt < 16; ++nt) {
        size_t base = (size_t)((b * 16 + nt) * 2) * 1024 + o;
        m = fmaxf(m, part[base]);
        s += part[base + 1024];
    }
    out[b * 2048 + o] = m;
    out[b * 2048 + 1024 + o] = s * (1.0f / 2048.0f);
}

// ---------------------------------------------------------------------------
extern "C" void kernel_launch(void* const* d_in, const int* in_sizes, int n_in,
                              void* d_out, int out_size, void* d_ws, size_t ws_size,
                              hipStream_t stream) {
    const float* points = (const float*)d_in[0];
    const float* W1 = (const float*)d_in[1];
    const float* W2 = (const float*)d_in[2];
    const float* W3 = (const float*)d_in[3];
    const float* W4 = (const float*)d_in[4];
    const float* W5 = (const float*)d_in[5];
    const float* g1 = (const float*)d_in[6];
    const float* b1 = (const float*)d_in[7];
    const float* g2 = (const float*)d_in[8];
    const float* b2 = (const float*)d_in[9];
    const float* g3 = (const float*)d_in[10];
    const float* b3 = (const float*)d_in[11];
    const float* g4 = (const float*)d_in[12];
    const float* b4 = (const float*)d_in[13];
    const float* g5 = (const float*)d_in[14];
    const float* b5 = (const float*)d_in[15];
    float* out = (float*)d_out;

    // ---- round-4 memory layout, verbatim ----
    const size_t f_xcat = (size_t)BN_TOTAL * 512;          // 8,388,608 floats
    const size_t f_w5 = (size_t)1024 * 512;                // 524,288 elems
    const size_t f_x2 = BN_TOTAL;
    const size_t f_idx = (size_t)BN_TOTAL * KNN;
    const size_t f_part = (size_t)8 * 16 * 2 * 1024;
    const size_t f_bf16 = f_xcat + f_w5;                   // in float units
    const size_t fixedf = f_xcat + f_x2 + f_idx + f_part + f_bf16;
    auto needB = [&](int c) {
        size_t spq = (size_t)c * NPTS * NPTS;
        if (spq < f_xcat) spq = f_xcat;
        return 4ull * (fixedf + spq);
    };
    int cB = 2;
    if (ws_size >= needB(8)) cB = 8;
    else if (ws_size >= needB(4)) cB = 4;
    size_t spq_f = (size_t)cB * NPTS * NPTS;
    if (spq_f < f_xcat) spq_f = f_xcat;

    float* xcat = (float*)d_ws;
    float* SPQ = xcat + f_xcat;
    float* x2 = SPQ + spq_f;
    int* idx = (int*)(x2 + f_x2);
    float* part = (float*)(idx + f_idx);
    unsigned short* Xhi = (unsigned short*)(part + f_part);
    unsigned short* Xlo = Xhi + f_xcat;
    unsigned short* Whi = Xlo + f_xcat;
    unsigned short* Wlo = Whi + f_w5;

    auto layer = [&](const float* xin, int C, int ldx, const float* W, int O, int oshift,
                     const float* ga, const float* be, float* xout) {
        x2_kernel<<<(BN_TOTAL + 255) / 256, 256, 0, stream>>>(xin, C, ldx, x2);
        // dist/topk: same addresses as round-4's single cB-wide dispatch, but
        // issued in 2-batch chunks so each dist->topk working set (33 MB) is
        // L3-resident. Pure launch-splitting; no layout/index changes.
        for (int b0 = 0; b0 < BATCH; b0 += cB) {
            for (int c0 = 0; c0 < cB; c0 += 2) {
                float* Sb = SPQ + (size_t)c0 * NPTS * NPTS;
                dist_kernel<<<dim3(16, 16, 2), 256, 0, stream>>>(xin, x2, C, ldx, b0 + c0, Sb);
                topk_kernel<<<2 * 512, 256, 0, stream>>>(Sb, b0 + c0, idx);
            }
        }
        pq_gemm<<<dim3(BN_TOTAL / 64, (2 * O) / 64), 256, 0, stream>>>(xin, C, ldx, W, O, SPQ);
        int rpb = 256 >> oshift;
        gmax_kernel<<<BN_TOTAL / rpb, 256, 0, stream>>>(SPQ, idx, O, oshift, ga, be, xout, 512);
    };

    layer(points,     3,   3,   W1, 64,  6, g1, b1, xcat + 0);
    layer(xcat + 0,   64,  512, W2, 64,  6, g2, b2, xcat + 64);
    layer(xcat + 64,  64,  512, W3, 128, 7, g3, b3, xcat + 128);
    layer(xcat + 128, 128, 512, W4, 256, 8, g4, b4, xcat + 256);

    split_bf16_kernel<<<(int)((f_xcat / 4 + 255) / 256), 256, 0, stream>>>(xcat, (int)(f_xcat / 4), Xhi, Xlo);
    split_bf16_kernel<<<(int)((f_w5 / 4 + 255) / 256), 256, 0, stream>>>(W5, (int)(f_w5 / 4), Whi, Wlo);
    final_mfma<<<dim3(BN_TOTAL / 128, 1024 / 128), 256, 0, stream>>>(Xhi, Xlo, Whi, Wlo, g5, b5, part);
    freduce_kernel<<<(8 * 1024 + 255) / 256, 256, 0, stream>>>(part, out);
}